// Round 1
// baseline (11936.729 us; speedup 1.0000x reference)
//
#include <hip/hip_runtime.h>
#include <math.h>

// Sizes: B=32, S=256, T=256, V=10000, E=512, H=1024, C=1024, SE=8
// in1 = E+SE+C = 1544, 3H = 3072, M = B*T = 8192 (row r = t*32 + b)

__device__ __forceinline__ float sigf(float x) { return 1.0f / (1.0f + __expf(-x)); }

// ---------------- prep: gather ctx/style, build concat vectors, zero b_seq[0] ----------------
__global__ void prep_kernel(const float* __restrict__ enc_output,
                            const int*   __restrict__ enc_len,
                            const int*   __restrict__ styles,
                            const float* __restrict__ style_table,
                            float* __restrict__ xA,     // [32][1032] = [ctx, style]  (for Wp)
                            float* __restrict__ xB,     // [32][1032] = [style, ctx]  (for Wih1[:,E:])
                            float* __restrict__ bseq0)  // [32][1024] zeros
{
    int b = blockIdx.x;
    int tid = threadIdx.x;
    int last = enc_len[b] - 1;
    last = last < 0 ? 0 : (last > 255 ? 255 : last);
    const float* ctx = enc_output + ((size_t)b * 256 + last) * 1024;
    for (int k = tid; k < 1024; k += blockDim.x) {
        float v = ctx[k];
        xA[b * 1032 + k]     = v;
        xB[b * 1032 + 8 + k] = v;
        bseq0[b * 1024 + k]  = 0.0f;
    }
    if (tid < 8) {
        float se = style_table[styles[b] * 8 + tid];
        xA[b * 1032 + 1024 + tid] = se;
        xB[b * 1032 + tid]        = se;
    }
}

// ---------------- generic fp32 GEMM: C[M,N] = A[M,K] * W^T (+bias +rowbase) ----------------
// BMODE 0: W is [N][ldb] (j-major rows, dot along K)   -> Wih*/Wp
// BMODE 1: W is [K][ldb=N] (k-major)                   -> Wout
// EPI 0: C[r*N + n];  EPI 1: logits layout out[(b*256+t)*N + n], b=r&31, t=r>>5
// GATHER 1: A row r = emb_table[dec_in[(r&31)*256 + (r>>5)]]
template<int BMODE, int EPI, int GATHER>
__global__ __launch_bounds__(256, 2)
void gemm128(const float* __restrict__ A, int lda,
             const float* __restrict__ W, int ldb,
             const float* __restrict__ bias,
             const float* __restrict__ rowbase,
             const int*   __restrict__ gidx,
             float* __restrict__ Cout,
             int M, int N, int K)
{
    __shared__ float As[8][132];
    __shared__ float Bs[8][132];
    const int tid = threadIdx.x;
    const int r0 = blockIdx.x * 128;
    const int n0 = blockIdx.y * 128;
    const int tx = tid & 15;
    const int ty = tid >> 4;

    float acc[8][8];
#pragma unroll
    for (int i = 0; i < 8; ++i)
#pragma unroll
        for (int j = 0; j < 8; ++j) acc[i][j] = 0.0f;

    const int am  = tid >> 1;
    const int akq = (tid & 1) * 4;
    const bool avalid = (r0 + am) < M;
    const float* arow;
    {
        int r = r0 + am; if (r >= M) r = M - 1;
        if (GATHER) {
            int idx = gidx[(r & 31) * 256 + (r >> 5)];
            arow = A + (size_t)idx * lda;
        } else {
            arow = A + (size_t)r * lda;
        }
    }

    for (int k0 = 0; k0 < K; k0 += 8) {
        float4 av = make_float4(0.f, 0.f, 0.f, 0.f);
        if (avalid) av = *(const float4*)(arow + k0 + akq);

        if (BMODE == 0) {
            const int ncol = tid >> 1;
            const int kq   = (tid & 1) * 4;
            float4 bv = make_float4(0.f, 0.f, 0.f, 0.f);
            int j = n0 + ncol;
            if (j < N) bv = *(const float4*)(W + (size_t)j * ldb + k0 + kq);
            __syncthreads();
            As[akq + 0][am] = av.x; As[akq + 1][am] = av.y;
            As[akq + 2][am] = av.z; As[akq + 3][am] = av.w;
            Bs[kq + 0][ncol] = bv.x; Bs[kq + 1][ncol] = bv.y;
            Bs[kq + 2][ncol] = bv.z; Bs[kq + 3][ncol] = bv.w;
        } else {
            const int kk = tid >> 5;
            const int nq = (tid & 31) * 4;
            float4 bv = make_float4(0.f, 0.f, 0.f, 0.f);
            int j = n0 + nq;
            if (j < N) bv = *(const float4*)(W + (size_t)(k0 + kk) * ldb + j);
            __syncthreads();
            As[akq + 0][am] = av.x; As[akq + 1][am] = av.y;
            As[akq + 2][am] = av.z; As[akq + 3][am] = av.w;
            *(float4*)&Bs[kk][nq] = bv;
        }
        __syncthreads();

#pragma unroll
        for (int kk = 0; kk < 8; ++kk) {
            float4 a0 = *(const float4*)&As[kk][ty * 8];
            float4 a1 = *(const float4*)&As[kk][ty * 8 + 4];
            float4 b0 = *(const float4*)&Bs[kk][tx * 8];
            float4 b1 = *(const float4*)&Bs[kk][tx * 8 + 4];
            float ar[8] = {a0.x, a0.y, a0.z, a0.w, a1.x, a1.y, a1.z, a1.w};
            float br[8] = {b0.x, b0.y, b0.z, b0.w, b1.x, b1.y, b1.z, b1.w};
#pragma unroll
            for (int i = 0; i < 8; ++i)
#pragma unroll
                for (int j = 0; j < 8; ++j)
                    acc[i][j] = fmaf(ar[i], br[j], acc[i][j]);
        }
    }

#pragma unroll
    for (int i = 0; i < 8; ++i) {
        int r = r0 + ty * 8 + i;
        if (r < M) {
            float* crow;
            if (EPI == 0) {
                crow = Cout + (size_t)r * N;
            } else {
                int bb = r & 31, tt = r >> 5;
                crow = Cout + ((size_t)(bb * 256 + tt)) * (size_t)N;
            }
            const float* rb = rowbase ? (rowbase + (size_t)(r & 31) * N) : nullptr;
#pragma unroll
            for (int jq = 0; jq < 2; ++jq) {
                int n = n0 + tx * 8 + jq * 4;
                if (n < N) {
                    float4 v;
                    v.x = acc[i][jq * 4 + 0]; v.y = acc[i][jq * 4 + 1];
                    v.z = acc[i][jq * 4 + 2]; v.w = acc[i][jq * 4 + 3];
                    if (bias) {
                        float4 bz = *(const float4*)(bias + n);
                        v.x += bz.x; v.y += bz.y; v.z += bz.z; v.w += bz.w;
                    }
                    if (rb) {
                        float4 rz = *(const float4*)(rb + n);
                        v.x += rz.x; v.y += rz.y; v.z += rz.z; v.w += rz.w;
                    }
                    *(float4*)(crow + n) = v;
                }
            }
        }
    }
}

// ---------------- one GRU step (gh GEMM + gates fused) ----------------
// gi: [32][3072] for this t (already contains x@Wih^T + bih (+base)); hprev/hout: [32][1024]
// grid 256 blocks (4 h-units each), 512 threads: (b: 32) x (hi: 4) x (ks: 4 K-quarters)
__global__ __launch_bounds__(512)
void gru_step(const float* __restrict__ gi,
              const float* __restrict__ hprev,
              const float* __restrict__ Whh,   // [3072][1024]
              const float* __restrict__ bhh,   // [3072]
              float* __restrict__ hout)
{
    __shared__ float hp[32][260];
    __shared__ float part[4][32][4][3];
    const int tid = threadIdx.x;
    const int b  = tid & 31;
    const int hi = (tid >> 5) & 3;
    const int ks = tid >> 7;
    const int h  = blockIdx.x * 4 + hi;

    const float* w0 = Whh + (size_t)h * 1024;
    const float* w1 = Whh + (size_t)(1024 + h) * 1024;
    const float* w2 = Whh + (size_t)(2048 + h) * 1024;

    const int sb = tid >> 4;
    const int sc = tid & 15;

    float acc0 = 0.f, acc1 = 0.f, acc2 = 0.f;

    for (int kt = 0; kt < 4; ++kt) {
        const int kbase = kt * 256;
        __syncthreads();
        {
            const float4* src = (const float4*)(hprev + sb * 1024 + kbase);
#pragma unroll
            for (int q = 0; q < 4; ++q) {
                float4 v = src[sc + q * 16];
                *(float4*)&hp[sb][(sc + q * 16) * 4] = v;
            }
        }
        __syncthreads();
        const float* ap  = &hp[b][ks * 64];
        const float* wk0 = w0 + kbase + ks * 64;
        const float* wk1 = w1 + kbase + ks * 64;
        const float* wk2 = w2 + kbase + ks * 64;
#pragma unroll
        for (int k = 0; k < 64; k += 4) {
            float4 a4 = *(const float4*)(ap + k);
            float4 x0 = *(const float4*)(wk0 + k);
            float4 x1 = *(const float4*)(wk1 + k);
            float4 x2 = *(const float4*)(wk2 + k);
            acc0 = fmaf(a4.x, x0.x, fmaf(a4.y, x0.y, fmaf(a4.z, x0.z, fmaf(a4.w, x0.w, acc0))));
            acc1 = fmaf(a4.x, x1.x, fmaf(a4.y, x1.y, fmaf(a4.z, x1.z, fmaf(a4.w, x1.w, acc1))));
            acc2 = fmaf(a4.x, x2.x, fmaf(a4.y, x2.y, fmaf(a4.z, x2.z, fmaf(a4.w, x2.w, acc2))));
        }
    }
    part[ks][b][hi][0] = acc0;
    part[ks][b][hi][1] = acc1;
    part[ks][b][hi][2] = acc2;
    __syncthreads();
    if (ks == 0) {
        float ghr = part[0][b][hi][0] + part[1][b][hi][0] + part[2][b][hi][0] + part[3][b][hi][0] + bhh[h];
        float ghz = part[0][b][hi][1] + part[1][b][hi][1] + part[2][b][hi][1] + part[3][b][hi][1] + bhh[1024 + h];
        float ghn = part[0][b][hi][2] + part[1][b][hi][2] + part[2][b][hi][2] + part[3][b][hi][2] + bhh[2048 + h];
        float gir = gi[b * 3072 + h];
        float giz = gi[b * 3072 + 1024 + h];
        float gin = gi[b * 3072 + 2048 + h];
        float r  = sigf(gir + ghr);
        float z  = sigf(giz + ghz);
        float nn = tanhf(gin + r * ghn);
        float hv = hprev[b * 1024 + h];
        hout[b * 1024 + h] = (1.0f - z) * nn + z * hv;
    }
}

// ---------------- fused log-softmax tail: lse, gather log-prob, argmax ----------------
__global__ __launch_bounds__(256)
void softmax_tail(const float* __restrict__ logits,  // [(b*256+t)][10000]
                  const int*   __restrict__ dec_out, // [32][256] flat = p
                  float* __restrict__ lp,
                  float* __restrict__ pred)
{
    const int p = blockIdx.x;
    const int tid = threadIdx.x;
    const float* row = logits + (size_t)p * 10000;

    float m = -INFINITY, s = 0.0f;
    int am = 0;
    for (int q = tid; q < 2500; q += 256) {
        float4 v = *(const float4*)(row + q * 4);
        float xs[4] = {v.x, v.y, v.z, v.w};
#pragma unroll
        for (int c = 0; c < 4; ++c) {
            float x = xs[c];
            if (x > m) {
                s = s * __expf(m - x) + 1.0f;
                m = x;
                am = q * 4 + c;
            } else {
                s += __expf(x - m);
            }
        }
    }
    __shared__ float sm[256];
    __shared__ float ss[256];
    __shared__ int   sa[256];
    sm[tid] = m; ss[tid] = s; sa[tid] = am;
    __syncthreads();
    for (int w = 128; w > 0; w >>= 1) {
        if (tid < w) {
            float m1 = sm[tid],     s1 = ss[tid];     int a1 = sa[tid];
            float m2 = sm[tid + w], s2 = ss[tid + w]; int a2 = sa[tid + w];
            float M2 = fmaxf(m1, m2);
            float S2 = s1 * __expf(m1 - M2) + s2 * __expf(m2 - M2);
            int A2;
            if (m1 > m2) A2 = a1;
            else if (m2 > m1) A2 = a2;
            else A2 = (a1 < a2) ? a1 : a2;
            sm[tid] = M2; ss[tid] = S2; sa[tid] = A2;
        }
        __syncthreads();
    }
    if (tid == 0) {
        float lse = sm[0] + logf(ss[0]);
        int tok = dec_out[p];
        lp[p]   = row[tok] - lse;
        pred[p] = (float)sa[0];
    }
}

extern "C" void kernel_launch(void* const* d_in, const int* in_sizes, int n_in,
                              void* d_out, int out_size, void* d_ws, size_t ws_size,
                              hipStream_t stream)
{
    const float* enc_output  = (const float*)d_in[0];
    const int*   enc_len     = (const int*)  d_in[1];
    const int*   styles      = (const int*)  d_in[2];
    const int*   dec_in      = (const int*)  d_in[3];
    const int*   dec_out     = (const int*)  d_in[4];
    const float* emb_table   = (const float*)d_in[5];
    const float* style_table = (const float*)d_in[6];
    const float* Wp   = (const float*)d_in[7];
    const float* bp   = (const float*)d_in[8];
    const float* Wih1 = (const float*)d_in[9];
    const float* Whh1 = (const float*)d_in[10];
    const float* bih1 = (const float*)d_in[11];
    const float* bhh1 = (const float*)d_in[12];
    const float* Wih2 = (const float*)d_in[13];
    const float* Whh2 = (const float*)d_in[14];
    const float* bih2 = (const float*)d_in[15];
    const float* bhh2 = (const float*)d_in[16];
    const float* Wout = (const float*)d_in[17];
    const float* bout = (const float*)d_in[18];

    float* out = (float*)d_out;

    // Scratch inside the logits region of d_out (dead before logits GEMM overwrites it):
    float* giBuf = out;                  // [8192][3072]            = 25,165,824 f
    float* aSeq  = out + 25165824;       // [257][32][1024]         =  8,421,376 f
    float* base1 = out + 33587200;       // [32][3072]              =     98,304 f
    float* xA    = out + 33685504;       // [32][1032]
    float* xB    = out + 33718528;       // [32][1032]  (ends 33,751,552 < 81,920,000)
    // b_seq must survive while logits are written -> lives in d_ws:
    float* bSeq  = (float*)d_ws;         // [257][32][1024] = 33.7 MB

    float* logitsOut = out;              // [32][256][10000]
    float* lpOut     = out + 81920000;   // [32][256]
    float* predOut   = out + 81928192;   // [32][256]

    // Phase 0: gather + concat vectors + zero b_seq slot 0
    prep_kernel<<<32, 256, 0, stream>>>(enc_output, enc_len, styles, style_table, xA, xB, bSeq);

    // h0 = xA @ Wp^T + bp  -> a_seq slot 0
    gemm128<0, 0, 0><<<dim3(1, 8), 256, 0, stream>>>(xA, 1032, Wp, 1032, bp, nullptr, nullptr,
                                                     aSeq, 32, 1024, 1032);
    // base1 = xB @ Wih1[:, 512:]^T + bih1
    gemm128<0, 0, 0><<<dim3(1, 24), 256, 0, stream>>>(xB, 1032, Wih1 + 512, 1544, bih1, nullptr, nullptr,
                                                      base1, 32, 3072, 1032);
    // gi1 = emb[dec_in] @ Wih1[:, :512]^T + base1[b]
    gemm128<0, 0, 1><<<dim3(64, 24), 256, 0, stream>>>(emb_table, 512, Wih1, 1544, nullptr, base1, dec_in,
                                                       giBuf, 8192, 3072, 512);
    // Layer-1 scan
    for (int t = 0; t < 256; ++t)
        gru_step<<<256, 512, 0, stream>>>(giBuf + (size_t)t * 98304,
                                          aSeq + (size_t)t * 32768,
                                          Whh1, bhh1,
                                          aSeq + (size_t)(t + 1) * 32768);
    // gi2 = a_seq[1:] @ Wih2^T + bih2  (reuses giBuf)
    gemm128<0, 0, 0><<<dim3(64, 24), 256, 0, stream>>>(aSeq + 32768, 1024, Wih2, 1024, bih2, nullptr, nullptr,
                                                       giBuf, 8192, 3072, 1024);
    // Layer-2 scan
    for (int t = 0; t < 256; ++t)
        gru_step<<<256, 512, 0, stream>>>(giBuf + (size_t)t * 98304,
                                          bSeq + (size_t)t * 32768,
                                          Whh2, bhh2,
                                          bSeq + (size_t)(t + 1) * 32768);
    // logits = b_seq[1:] @ Wout + bout, written in [b][t][v] order
    gemm128<1, 1, 0><<<dim3(64, 79), 256, 0, stream>>>(bSeq + 32768, 1024, Wout, 10000, bout, nullptr, nullptr,
                                                       logitsOut, 8192, 10000, 1024);
    // log-softmax gather + argmax
    softmax_tail<<<8192, 256, 0, stream>>>(logitsOut, dec_out, lpOut, predOut);
}